// Round 13
// baseline (289.348 us; speedup 1.0000x reference)
//
#include <hip/hip_runtime.h>

#define B_   2
#define D_   32
#define H_   256
#define W_   256
#define N_   150000
#define CIN  16
#define CMID 32
#define COUT 64
#define DO_  16
#define HO_  128
#define WO_  128
#define M_   (B_*DO_*HO_*WO_)   /* 524288 */
#define EPSf 1e-5f
#define NB_DOWN 8192             /* k_down blocks; %8==0, 64 voxels per block */
#define NREP 64                  /* stats slabs (atomic de-contention) */

typedef _Float16 h2 __attribute__((ext_vector_type(2)));
__device__ inline h2 as_h2(unsigned u) { union { unsigned u; h2 h; } x; x.u = u; return x.h; }

#if defined(__has_builtin) && __has_builtin(__builtin_amdgcn_fdot2)
__device__ inline float dot2(unsigned f, unsigned w, float acc) {
    return __builtin_amdgcn_fdot2(as_h2(f), as_h2(w), acc, false);
}
#else
__device__ inline float dot2(unsigned f, unsigned w, float acc) {
    const h2 a = as_h2(f), b = as_h2(w);
    return fmaf((float)a.x, (float)b.x, fmaf((float)a.y, (float)b.y, acc));
}
#endif

// pack two floats into one dword of fp16 (RNE via _Float16 cast)
__device__ inline unsigned hpk(float a, float b) {
    union { _Float16 h[2]; unsigned u; } x;
    x.h[0] = (_Float16)a; x.h[1] = (_Float16)b; return x.u;
}

// ---------------- grid scatter ----------------
__global__ __launch_bounds__(256) void k_scatter(const int* __restrict__ coords,
                                                 int* __restrict__ grid) {
    int i = blockIdx.x * 256 + threadIdx.x;
    if (i >= N_) return;
    const int4 c = *(const int4*)(coords + 4 * (size_t)i);
    grid[((c.x * D_ + c.y) * H_ + c.z) * W_ + c.w] = i;
}

// ---------------- weight transpose+pack to fp16 pairs ----------------
__global__ __launch_bounds__(256) void k_twisth(const float* __restrict__ W1,
                                                const float* __restrict__ W2,
                                                const float* __restrict__ W3,
                                                uint4* __restrict__ Wh1,
                                                uint4* __restrict__ Wh2,
                                                uint4* __restrict__ Wh3) {
    const int t = blockIdx.x * 256 + threadIdx.x;
    if (t < 1728) {
        const int ki = t / 64, r = t % 64, half = r >> 5, sub = r & 31;
        const float* base = W1 + ki * 512 + (half * 8) * 32 + sub;
        uint4 o;
        o.x = hpk(base[0],   base[32]);
        o.y = hpk(base[64],  base[96]);
        o.z = hpk(base[128], base[160]);
        o.w = hpk(base[192], base[224]);
        Wh1[(ki * 2 + half) * 32 + sub] = o;
    } else if (t < 1728 + 3456) {
        const int u = t - 1728;
        const int ki = u / 128, r = u % 128, qh = r >> 5, sub = r & 31;
        const int half = qh >> 1, q = qh & 1;
        const float* base = W2 + ki * 1024 + (half * 16 + q * 8) * 32 + sub;
        uint4 o;
        o.x = hpk(base[0],   base[32]);
        o.y = hpk(base[64],  base[96]);
        o.z = hpk(base[128], base[160]);
        o.w = hpk(base[192], base[224]);
        Wh2[((ki * 2 + half) * 2 + q) * 32 + sub] = o;
    } else if (t < 1728 + 3456 + 6912) {
        const int u = t - 5184;
        const int ki = u / 256, r = u % 256, q = r >> 6, lane = r & 63;
        const float* base = W3 + ki * 2048 + (q * 8) * 64 + lane;
        uint4 o;
        o.x = hpk(base[0],   base[64]);
        o.y = hpk(base[128], base[192]);
        o.z = hpk(base[256], base[320]);
        o.w = hpk(base[384], base[448]);
        Wh3[(ki * 4 + q) * 64 + lane] = o;
    }
}

// ---------------- feats fp32 -> fp16 pack ----------------
__global__ __launch_bounds__(256) void k_feat16(const float* __restrict__ F,
                                                unsigned* __restrict__ F16) {
    const int i = blockIdx.x * 256 + threadIdx.x;   // one float4 -> uint2
    if (i >= N_ * CIN / 4) return;
    const float4 v = ((const float4*)F)[i];
    uint2 o; o.x = hpk(v.x, v.y); o.y = hpk(v.z, v.w);
    ((uint2*)F16)[i] = o;
}

// ------- submanifold conv: 4 points/wave, branched 4-chain, fused stats -----
template <int CI>
__global__ __launch_bounds__(256) void k_subm(const unsigned* __restrict__ X16,
                                              const int* __restrict__ coords,
                                              const int* __restrict__ grid,
                                              const uint4* __restrict__ Wh,
                                              const float* __restrict__ bias,
                                              _Float16* __restrict__ Yp,
                                              float* __restrict__ slab0) {
    constexpr int NQ = CI / 16;   // uint4 loads per tap per lane (1 or 2)
    const int wid  = (blockIdx.x * 256 + threadIdx.x) >> 6;
    const int lane = threadIdx.x & 63;
    const int sub  = lane & 31;
    const int half = lane >> 5;
    const int i0   = wid * 4;

    int nidx01 = -1, nidx23 = -1;
    {
        const int4 cc = *(const int4*)(coords + 4 * (size_t)(i0 + half));
        if (sub < 27) {
            const int nz = cc.y + sub / 9 - 1;
            const int ny = cc.z + (sub / 3) % 3 - 1;
            const int nx = cc.w + sub % 3 - 1;
            if ((unsigned)nz < (unsigned)D_ && (unsigned)ny < (unsigned)H_ &&
                (unsigned)nx < (unsigned)W_)
                nidx01 = grid[((cc.x * D_ + nz) * H_ + ny) * W_ + nx];
        }
    }
    {
        const int4 cc = *(const int4*)(coords + 4 * (size_t)(i0 + 2 + half));
        if (sub < 27) {
            const int nz = cc.y + sub / 9 - 1;
            const int ny = cc.z + (sub / 3) % 3 - 1;
            const int nx = cc.w + sub % 3 - 1;
            if ((unsigned)nz < (unsigned)D_ && (unsigned)ny < (unsigned)H_ &&
                (unsigned)nx < (unsigned)W_)
                nidx23 = grid[((cc.x * D_ + nz) * H_ + ny) * W_ + nx];
        }
    }
    const unsigned long long a01 = __ballot(nidx01 >= 0);
    const unsigned long long a23 = __ballot(nidx23 >= 0);
    unsigned m0 = (unsigned)a01 & 0x7FFFFFFu;
    unsigned m1 = (unsigned)(a01 >> 32) & 0x7FFFFFFu;
    unsigned m2 = (unsigned)a23 & 0x7FFFFFFu;
    unsigned m3 = (unsigned)(a23 >> 32) & 0x7FFFFFFu;

    float acc0 = 0.f, acc1 = 0.f, acc2 = 0.f, acc3 = 0.f;

    auto tap = [&](int ki, int ni, float& acc) {
        const uint4* __restrict__ f =
            (const uint4*)(X16 + (size_t)ni * (CI / 2) + half * (CI / 4));
        const uint4* __restrict__ wb = Wh + ((size_t)(ki * 2 + half)) * NQ * 32 + sub;
#pragma unroll
        for (int q = 0; q < NQ; ++q) {
            const uint4 fu = f[q];
            const uint4 wu = wb[q * 32];
            acc = dot2(fu.x, wu.x, acc);
            acc = dot2(fu.y, wu.y, acc);
            acc = dot2(fu.z, wu.z, acc);
            acc = dot2(fu.w, wu.w, acc);
        }
    };

    while (m0 | m1 | m2 | m3) {
        if (m0) { const int ki = __builtin_ctz(m0); m0 &= m0 - 1;
                  tap(ki, __shfl(nidx01, ki, 64),      acc0); }
        if (m1) { const int ki = __builtin_ctz(m1); m1 &= m1 - 1;
                  tap(ki, __shfl(nidx01, ki + 32, 64), acc1); }
        if (m2) { const int ki = __builtin_ctz(m2); m2 &= m2 - 1;
                  tap(ki, __shfl(nidx23, ki, 64),      acc2); }
        if (m3) { const int ki = __builtin_ctz(m3); m3 &= m3 - 1;
                  tap(ki, __shfl(nidx23, ki + 32, 64), acc3); }
    }

    acc0 += __shfl_xor(acc0, 32, 64);
    acc1 += __shfl_xor(acc1, 32, 64);
    acc2 += __shfl_xor(acc2, 32, 64);
    acc3 += __shfl_xor(acc3, 32, 64);
    const float bv  = bias[sub];
    const float o01 = (half ? acc1 : acc0) + bv;   // point i0+half
    const float o23 = (half ? acc3 : acc2) + bv;   // point i0+2+half
    Yp[(size_t)(i0 + half) * 32 + sub]     = (_Float16)o01;
    Yp[(size_t)(i0 + 2 + half) * 32 + sub] = (_Float16)o23;

    // fused BN stats into NREP slabs
    __shared__ float sd[256];
    const int tid = threadIdx.x;
    float* __restrict__ slab = slab0 + (size_t)(blockIdx.x & (NREP - 1)) * 64;
    sd[tid] = o01 + o23;
    __syncthreads();
    if (tid < 32) {
        float t = 0.f;
#pragma unroll
        for (int k = 0; k < 8; ++k) t += sd[tid + 32 * k];
        atomicAdd(slab + tid, t);
    }
    __syncthreads();
    sd[tid] = o01 * o01 + o23 * o23;
    __syncthreads();
    if (tid < 32) {
        float t = 0.f;
#pragma unroll
        for (int k = 0; k < 8; ++k) t += sd[tid + 32 * k];
        atomicAdd(slab + 32 + tid, t);
    }
}

// ------ strided down conv: LDS grid rows, 4-chain, VECTOR feature loads -----
// R12 lesson: readfirstlane->s_load routed every tap's 64B feature read through
// the tiny shared scalar K$ (miss-serialized). Vector uint4 loads of the same
// uniform address coalesce to one 64B request through the per-CU vL1.
__global__ __launch_bounds__(256) void k_down(const unsigned* __restrict__ X16,
                                              const int* __restrict__ grid,
                                              const uint4* __restrict__ Wh3,
                                              const float* __restrict__ bias,
                                              _Float16* __restrict__ Yh,
                                              unsigned char* __restrict__ mask,
                                              float* __restrict__ slab0,
                                              int* __restrict__ nacts) {
    const int b    = blockIdx.x;
    const int swz  = (b & 7) * (NB_DOWN / 8) + (b >> 3);
    const int tid  = threadIdx.x;
    const int wv   = tid >> 6;
    const int lane = tid & 63;
    const int sub  = lane & 31;
    const int half = lane >> 5;

    const int vox0 = swz * 64;
    const int ox0  = vox0 & 127;      // 0 or 64
    int t = vox0 >> 7;
    const int oy = t & 127; t >>= 7;
    const int oz = t & 15;
    const int bb = t >> 4;

    __shared__ int   gl[9][132];
    __shared__ float sd[256];
    __shared__ int   scnt[4];

    const int gx0 = 2 * ox0 - 1;
    for (int e = tid; e < 9 * 132; e += 256) {
        const int r  = e / 132, xo = e % 132;
        const int z  = 2 * oz - 1 + r / 3;
        const int y  = 2 * oy - 1 + r % 3;
        const int x  = gx0 + xo;
        int v = -1;
        if ((unsigned)z < (unsigned)D_ && (unsigned)y < (unsigned)H_ &&
            (unsigned)x < (unsigned)W_ && xo < 129)
            v = grid[((bb * D_ + z) * H_ + y) * W_ + x];
        gl[r][xo] = v;
    }
    __syncthreads();

    const int dz = sub / 9, dy = (sub / 3) % 3, dx = sub % 3;
    const int row = (sub < 27) ? dz * 3 + dy : 0;

    const float bv = bias[lane];
    float s = 0.f, s2 = 0.f;
    int cnt = 0;

    auto tap = [&](int ki, int ni, float& acc) {
        const uint4* __restrict__ fS = (const uint4*)(X16 + (size_t)ni * 16);
        const uint4* __restrict__ wb = Wh3 + (size_t)ki * 256 + lane;
#pragma unroll
        for (int q = 0; q < 4; ++q) {
            const uint4 fu = fS[q];
            const uint4 wu = wb[q * 64];
            acc = dot2(fu.x, wu.x, acc);
            acc = dot2(fu.y, wu.y, acc);
            acc = dot2(fu.z, wu.z, acc);
            acc = dot2(fu.w, wu.w, acc);
        }
    };

    for (int it = 0; it < 4; ++it) {
        const int v0 = wv * 16 + it * 4;   // 4 voxels this iteration
        const int n01 = (sub < 27) ? gl[row][2 * (v0 + half) + dx] : -1;
        const int n23 = (sub < 27) ? gl[row][2 * (v0 + 2 + half) + dx] : -1;
        const unsigned long long a01 = __ballot(n01 >= 0);
        const unsigned long long a23 = __ballot(n23 >= 0);
        unsigned m0 = (unsigned)a01 & 0x7FFFFFFu;
        unsigned m1 = (unsigned)(a01 >> 32) & 0x7FFFFFFu;
        unsigned m2 = (unsigned)a23 & 0x7FFFFFFu;
        unsigned m3 = (unsigned)(a23 >> 32) & 0x7FFFFFFu;
        const int mk0 = m0 ? 1 : 0, mk1 = m1 ? 1 : 0;
        const int mk2 = m2 ? 1 : 0, mk3 = m3 ? 1 : 0;

        float ac0 = 0.f, ac1 = 0.f, ac2 = 0.f, ac3 = 0.f;
        while (m0 | m1 | m2 | m3) {
            if (m0) { const int ki = __builtin_ctz(m0); m0 &= m0 - 1;
                      tap(ki, __shfl(n01, ki, 64),      ac0); }
            if (m1) { const int ki = __builtin_ctz(m1); m1 &= m1 - 1;
                      tap(ki, __shfl(n01, ki + 32, 64), ac1); }
            if (m2) { const int ki = __builtin_ctz(m2); m2 &= m2 - 1;
                      tap(ki, __shfl(n23, ki, 64),      ac2); }
            if (m3) { const int ki = __builtin_ctz(m3); m3 &= m3 - 1;
                      tap(ki, __shfl(n23, ki + 32, 64), ac3); }
        }

        const int vg = vox0 + v0;
        const float o0 = mk0 ? ac0 + bv : 0.f;
        const float o1 = mk1 ? ac1 + bv : 0.f;
        const float o2 = mk2 ? ac2 + bv : 0.f;
        const float o3 = mk3 ? ac3 + bv : 0.f;
        Yh[(size_t)vg * COUT + lane]       = (_Float16)o0;
        Yh[(size_t)(vg + 1) * COUT + lane] = (_Float16)o1;
        Yh[(size_t)(vg + 2) * COUT + lane] = (_Float16)o2;
        Yh[(size_t)(vg + 3) * COUT + lane] = (_Float16)o3;
        if (lane == 0) {
            mask[vg]     = (unsigned char)mk0;
            mask[vg + 1] = (unsigned char)mk1;
            mask[vg + 2] = (unsigned char)mk2;
            mask[vg + 3] = (unsigned char)mk3;
            cnt += mk0 + mk1 + mk2 + mk3;
        }
        s  += o0 + o1 + o2 + o3;
        s2 += o0 * o0 + o1 * o1 + o2 * o2 + o3 * o3;
    }

    float* __restrict__ slab = slab0 + (size_t)(b & (NREP - 1)) * 128;
    sd[tid] = s;
    if (lane == 0) scnt[wv] = cnt;
    __syncthreads();
    if (tid < 64) atomicAdd(slab + tid, sd[tid] + sd[tid + 64] + sd[tid + 128] + sd[tid + 192]);
    __syncthreads();
    sd[tid] = s2;
    __syncthreads();
    if (tid < 64) atomicAdd(slab + 64 + tid, sd[tid] + sd[tid + 64] + sd[tid + 128] + sd[tid + 192]);
    if (tid == 0) atomicAdd(nacts + (b & (NREP - 1)), scnt[0] + scnt[1] + scnt[2] + scnt[3]);
}

// ---------------- finalize scale/shift from NREP slabs (stages 1,2) ---------
template <int C>
__global__ void k_finslab(const float* __restrict__ slab0,
                          const float* __restrict__ g,
                          const float* __restrict__ be,
                          float n, float* __restrict__ ss) {
    const int c = threadIdx.x;
    if (c >= C) return;
    float sm = 0.f, s2 = 0.f;
    for (int r = 0; r < NREP; ++r) {
        sm += slab0[r * 2 * C + c];
        s2 += slab0[r * 2 * C + C + c];
    }
    const float m  = sm / n;
    const float v  = s2 / n - m * m;
    const float sc = g[c] * rsqrtf(v + EPSf);
    ss[c]     = sc;
    ss[C + c] = be[c] - m * sc;
}

// ---------------- finalize scale/shift (stage 3, folds NREP replicas) -------
__global__ void k_finstats3(const float* __restrict__ slab0,
                            const int* __restrict__ nacts,
                            const float* __restrict__ g,
                            const float* __restrict__ be,
                            float* __restrict__ ss) {
    const int c = threadIdx.x;   // 64 threads
    if (c >= 64) return;
    float sm = 0.f, s2 = 0.f;
    int na = 0;
    for (int r = 0; r < NREP; ++r) {
        sm += slab0[r * 128 + c];
        s2 += slab0[r * 128 + 64 + c];
        na += nacts[r];
    }
    const float n  = (float)(na > 0 ? na : 1);
    const float m  = sm / n;
    const float v  = s2 / n - m * m;
    const float sc = g[c] * rsqrtf(v + EPSf);
    ss[c]      = sc;
    ss[64 + c] = be[c] - m * sc;
}

// --------- normalize (BN+ReLU): fp16 pre-norm in -> packed fp16 out ---------
template <int C>
__global__ __launch_bounds__(256) void k_norm16(const unsigned* __restrict__ Yp2,
                                                const float* __restrict__ ss,
                                                unsigned* __restrict__ Xo16, long n4) {
    const long t = (long)blockIdx.x * 256 + threadIdx.x;
    if (t >= n4) return;
    const uint2 y = ((const uint2*)Yp2)[t];
    const h2 lo = as_h2(y.x), hi = as_h2(y.y);
    const int ch = (int)((t * 4) % C);
    float ox = fmaxf(fmaf((float)lo.x, ss[ch],     ss[C + ch]),     0.f);
    float oy = fmaxf(fmaf((float)lo.y, ss[ch + 1], ss[C + ch + 1]), 0.f);
    float oz = fmaxf(fmaf((float)hi.x, ss[ch + 2], ss[C + ch + 2]), 0.f);
    float ow = fmaxf(fmaf((float)hi.y, ss[ch + 3], ss[C + ch + 3]), 0.f);
    uint2 o; o.x = hpk(ox, oy); o.y = hpk(oz, ow);
    ((uint2*)Xo16)[t] = o;
}

// ---------------- stage-3 normalize: fp16 in, fp32 out ----------------
__global__ __launch_bounds__(256) void k_norm3(const _Float16* __restrict__ Yh,
                                               const unsigned char* __restrict__ mask,
                                               const float* __restrict__ ss,
                                               float* __restrict__ out) {
    const long n4 = (long)M_ * COUT / 4;
    const long t = (long)blockIdx.x * 256 + threadIdx.x;
    if (t >= n4) return;
    const long vox = t >> 4;
    const int ch = (int)((t * 4) & 63);
    float4 o;
    if (mask[vox]) {
        const uint2 yu = *(const uint2*)(Yh + t * 4);
        const h2 ylo = as_h2(yu.x), yhi = as_h2(yu.y);
        o.x = fmaxf(fmaf((float)ylo.x, ss[ch],     ss[64 + ch]),     0.f);
        o.y = fmaxf(fmaf((float)ylo.y, ss[ch + 1], ss[64 + ch + 1]), 0.f);
        o.z = fmaxf(fmaf((float)yhi.x, ss[ch + 2], ss[64 + ch + 2]), 0.f);
        o.w = fmaxf(fmaf((float)yhi.y, ss[ch + 3], ss[64 + ch + 3]), 0.f);
    } else {
        o.x = o.y = o.z = o.w = 0.f;
    }
    ((float4*)out)[t] = o;
}

extern "C" void kernel_launch(void* const* d_in, const int* in_sizes, int n_in,
                              void* d_out, int out_size, void* d_ws, size_t ws_size,
                              hipStream_t stream) {
    const float* feats = (const float*)d_in[0];
    const int*   coords = (const int*)d_in[1];
    const float* W1 = (const float*)d_in[2];
    const float* b1 = (const float*)d_in[3];
    const float* g1 = (const float*)d_in[4];
    const float* be1 = (const float*)d_in[5];
    const float* W2 = (const float*)d_in[6];
    const float* b2 = (const float*)d_in[7];
    const float* g2 = (const float*)d_in[8];
    const float* be2 = (const float*)d_in[9];
    const float* W3 = (const float*)d_in[10];
    const float* b3 = (const float*)d_in[11];
    const float* g3 = (const float*)d_in[12];
    const float* be3 = (const float*)d_in[13];
    float* out = (float*)d_out;

    char* ws = (char*)d_ws;
    const size_t gridBytes = (size_t)B_ * D_ * H_ * W_ * 4;   // 16,777,216
    const size_t f16Bytes  = (size_t)N_ * CIN * 2;            //  4,800,000
    const size_t bufPBytes = (size_t)N_ * CMID * 2;           //  9,600,000
    const size_t YhBytes   = (size_t)M_ * COUT * 2;           // 67,108,864
    int*       grid   = (int*)ws;
    unsigned*  feat16 = (unsigned*)(ws + gridBytes);
    _Float16*  bufP   = (_Float16*)(ws + gridBytes + f16Bytes);             // pre-norm
    unsigned*  bufH   = (unsigned*)(ws + gridBytes + f16Bytes + bufPBytes); // normalized
    _Float16*  Yh     = (_Float16*)(ws + gridBytes + f16Bytes + 2 * bufPBytes);
    unsigned char* mask = (unsigned char*)(ws + gridBytes + f16Bytes + 2 * bufPBytes + YhBytes);
    float* stats = (float*)(ws + gridBytes + f16Bytes + 2 * bufPBytes + YhBytes + (size_t)M_);

    float* ss1   = stats;                 // 64
    float* ss2   = stats + 64;            // 64
    float* ss3   = stats + 128;           // 128
    float* slab1 = stats + 1024;                        // NREP*64
    float* slab2 = stats + 1024 + NREP * 64;            // NREP*64
    float* slab3 = stats + 1024 + NREP * 128;           // NREP*128
    int*   nacts = (int*)(stats + 1024 + NREP * 256);   // NREP ints
    uint4* Wh1 = (uint4*)(stats + 32768);               // 1728 uint4
    uint4* Wh2 = Wh1 + 1728;                            // 3456 uint4
    uint4* Wh3 = Wh2 + 3456;                            // 6912 uint4

    hipMemsetAsync(grid, 0xFF, gridBytes, stream);
    hipMemsetAsync(stats + 1024, 0, (NREP * 256 + NREP) * 4, stream); // slabs+nacts

    k_scatter<<<(N_ + 255) / 256, 256, 0, stream>>>(coords, grid);
    k_twisth<<<(12096 + 255) / 256, 256, 0, stream>>>(W1, W2, W3, Wh1, Wh2, Wh3);
    k_feat16<<<(N_ * CIN / 4 + 255) / 256, 256, 0, stream>>>(feats, feat16);

    const int nb_subm = N_ / 16;   // 9375 blocks: 4 waves x 4 points, exact
    k_subm<CIN><<<nb_subm, 256, 0, stream>>>(feat16, coords, grid, Wh1, b1, bufP, slab1);
    k_finslab<CMID><<<1, 64, 0, stream>>>(slab1, g1, be1, (float)N_, ss1);
    k_norm16<CMID><<<(N_ * CMID / 4 + 255) / 256, 256, 0, stream>>>(
        (const unsigned*)bufP, ss1, bufH, (long)N_ * CMID / 4);

    k_subm<CMID><<<nb_subm, 256, 0, stream>>>(bufH, coords, grid, Wh2, b2, bufP, slab2);
    k_finslab<CMID><<<1, 64, 0, stream>>>(slab2, g2, be2, (float)N_, ss2);
    k_norm16<CMID><<<(N_ * CMID / 4 + 255) / 256, 256, 0, stream>>>(
        (const unsigned*)bufP, ss2, bufH, (long)N_ * CMID / 4);

    k_down<<<NB_DOWN, 256, 0, stream>>>(bufH, grid, Wh3, b3, Yh, mask, slab3, nacts);
    k_finstats3<<<1, 64, 0, stream>>>(slab3, nacts, g3, be3, ss3);
    k_norm3<<<(M_ * COUT / 4) / 256, 256, 0, stream>>>(Yh, mask, ss3, out);
}

// Round 14
// 238.865 us; speedup vs baseline: 1.2113x; 1.2113x over previous
//
#include <hip/hip_runtime.h>

#define B_   2
#define D_   32
#define H_   256
#define W_   256
#define N_   150000
#define CIN  16
#define CMID 32
#define COUT 64
#define DO_  16
#define HO_  128
#define WO_  128
#define M_   (B_*DO_*HO_*WO_)   /* 524288 */
#define EPSf 1e-5f
#define NB_DOWN 8192             /* k_down blocks; %8==0, 64 voxels per block */
#define NREP 64                  /* stats slabs (atomic de-contention) */

typedef _Float16 h2 __attribute__((ext_vector_type(2)));
__device__ inline h2 as_h2(unsigned u) { union { unsigned u; h2 h; } x; x.u = u; return x.h; }

#if defined(__has_builtin) && __has_builtin(__builtin_amdgcn_fdot2)
__device__ inline float dot2(unsigned f, unsigned w, float acc) {
    return __builtin_amdgcn_fdot2(as_h2(f), as_h2(w), acc, false);
}
#else
__device__ inline float dot2(unsigned f, unsigned w, float acc) {
    const h2 a = as_h2(f), b = as_h2(w);
    return fmaf((float)a.x, (float)b.x, fmaf((float)a.y, (float)b.y, acc));
}
#endif

// pack two floats into one dword of fp16 (RNE via _Float16 cast)
__device__ inline unsigned hpk(float a, float b) {
    union { _Float16 h[2]; unsigned u; } x;
    x.h[0] = (_Float16)a; x.h[1] = (_Float16)b; return x.u;
}

// ---------------- grid scatter ----------------
__global__ __launch_bounds__(256) void k_scatter(const int* __restrict__ coords,
                                                 int* __restrict__ grid) {
    int i = blockIdx.x * 256 + threadIdx.x;
    if (i >= N_) return;
    const int4 c = *(const int4*)(coords + 4 * (size_t)i);
    grid[((c.x * D_ + c.y) * H_ + c.z) * W_ + c.w] = i;
}

// ---------------- weight transpose+pack to fp16 pairs ----------------
__global__ __launch_bounds__(256) void k_twisth(const float* __restrict__ W1,
                                                const float* __restrict__ W2,
                                                const float* __restrict__ W3,
                                                uint4* __restrict__ Wh1,
                                                uint4* __restrict__ Wh2,
                                                uint4* __restrict__ Wh3) {
    const int t = blockIdx.x * 256 + threadIdx.x;
    if (t < 1728) {
        const int ki = t / 64, r = t % 64, half = r >> 5, sub = r & 31;
        const float* base = W1 + ki * 512 + (half * 8) * 32 + sub;
        uint4 o;
        o.x = hpk(base[0],   base[32]);
        o.y = hpk(base[64],  base[96]);
        o.z = hpk(base[128], base[160]);
        o.w = hpk(base[192], base[224]);
        Wh1[(ki * 2 + half) * 32 + sub] = o;
    } else if (t < 1728 + 3456) {
        const int u = t - 1728;
        const int ki = u / 128, r = u % 128, qh = r >> 5, sub = r & 31;
        const int half = qh >> 1, q = qh & 1;
        const float* base = W2 + ki * 1024 + (half * 16 + q * 8) * 32 + sub;
        uint4 o;
        o.x = hpk(base[0],   base[32]);
        o.y = hpk(base[64],  base[96]);
        o.z = hpk(base[128], base[160]);
        o.w = hpk(base[192], base[224]);
        Wh2[((ki * 2 + half) * 2 + q) * 32 + sub] = o;
    } else if (t < 1728 + 3456 + 6912) {
        const int u = t - 5184;
        const int ki = u / 256, r = u % 256, q = r >> 6, lane = r & 63;
        const float* base = W3 + ki * 2048 + (q * 8) * 64 + lane;
        uint4 o;
        o.x = hpk(base[0],   base[64]);
        o.y = hpk(base[128], base[192]);
        o.z = hpk(base[256], base[320]);
        o.w = hpk(base[384], base[448]);
        Wh3[(ki * 4 + q) * 64 + lane] = o;
    }
}

// ---------------- feats fp32 -> fp16 pack ----------------
__global__ __launch_bounds__(256) void k_feat16(const float* __restrict__ F,
                                                unsigned* __restrict__ F16) {
    const int i = blockIdx.x * 256 + threadIdx.x;   // one float4 -> uint2
    if (i >= N_ * CIN / 4) return;
    const float4 v = ((const float4*)F)[i];
    uint2 o; o.x = hpk(v.x, v.y); o.y = hpk(v.z, v.w);
    ((uint2*)F16)[i] = o;
}

// ------- submanifold conv: 4 points/wave, branched 4-chain, fused stats -----
// float4 accumulators: per-tap dependent dot2 chain is 4 (not 16) deep.
template <int CI>
__global__ __launch_bounds__(256) void k_subm(const unsigned* __restrict__ X16,
                                              const int* __restrict__ coords,
                                              const int* __restrict__ grid,
                                              const uint4* __restrict__ Wh,
                                              const float* __restrict__ bias,
                                              _Float16* __restrict__ Yp,
                                              float* __restrict__ slab0) {
    constexpr int NQ = CI / 16;   // uint4 loads per tap per lane (1 or 2)
    const int wid  = (blockIdx.x * 256 + threadIdx.x) >> 6;
    const int lane = threadIdx.x & 63;
    const int sub  = lane & 31;
    const int half = lane >> 5;
    const int i0   = wid * 4;

    int nidx01 = -1, nidx23 = -1;
    {
        const int4 cc = *(const int4*)(coords + 4 * (size_t)(i0 + half));
        if (sub < 27) {
            const int nz = cc.y + sub / 9 - 1;
            const int ny = cc.z + (sub / 3) % 3 - 1;
            const int nx = cc.w + sub % 3 - 1;
            if ((unsigned)nz < (unsigned)D_ && (unsigned)ny < (unsigned)H_ &&
                (unsigned)nx < (unsigned)W_)
                nidx01 = grid[((cc.x * D_ + nz) * H_ + ny) * W_ + nx];
        }
    }
    {
        const int4 cc = *(const int4*)(coords + 4 * (size_t)(i0 + 2 + half));
        if (sub < 27) {
            const int nz = cc.y + sub / 9 - 1;
            const int ny = cc.z + (sub / 3) % 3 - 1;
            const int nx = cc.w + sub % 3 - 1;
            if ((unsigned)nz < (unsigned)D_ && (unsigned)ny < (unsigned)H_ &&
                (unsigned)nx < (unsigned)W_)
                nidx23 = grid[((cc.x * D_ + nz) * H_ + ny) * W_ + nx];
        }
    }
    const unsigned long long a01 = __ballot(nidx01 >= 0);
    const unsigned long long a23 = __ballot(nidx23 >= 0);
    unsigned m0 = (unsigned)a01 & 0x7FFFFFFu;
    unsigned m1 = (unsigned)(a01 >> 32) & 0x7FFFFFFu;
    unsigned m2 = (unsigned)a23 & 0x7FFFFFFu;
    unsigned m3 = (unsigned)(a23 >> 32) & 0x7FFFFFFu;

    float4 ac0 = {0.f, 0.f, 0.f, 0.f}, ac1 = {0.f, 0.f, 0.f, 0.f};
    float4 ac2 = {0.f, 0.f, 0.f, 0.f}, ac3 = {0.f, 0.f, 0.f, 0.f};

    auto tap = [&](int ki, int ni, float4& ac) {
        const uint4* __restrict__ f =
            (const uint4*)(X16 + (size_t)ni * (CI / 2) + half * (CI / 4));
        const uint4* __restrict__ wb = Wh + ((size_t)(ki * 2 + half)) * NQ * 32 + sub;
#pragma unroll
        for (int q = 0; q < NQ; ++q) {
            const uint4 fu = f[q];
            const uint4 wu = wb[q * 32];
            ac.x = dot2(fu.x, wu.x, ac.x);
            ac.y = dot2(fu.y, wu.y, ac.y);
            ac.z = dot2(fu.z, wu.z, ac.z);
            ac.w = dot2(fu.w, wu.w, ac.w);
        }
    };

    while (m0 | m1 | m2 | m3) {
        if (m0) { const int ki = __builtin_ctz(m0); m0 &= m0 - 1;
                  tap(ki, __shfl(nidx01, ki, 64),      ac0); }
        if (m1) { const int ki = __builtin_ctz(m1); m1 &= m1 - 1;
                  tap(ki, __shfl(nidx01, ki + 32, 64), ac1); }
        if (m2) { const int ki = __builtin_ctz(m2); m2 &= m2 - 1;
                  tap(ki, __shfl(nidx23, ki, 64),      ac2); }
        if (m3) { const int ki = __builtin_ctz(m3); m3 &= m3 - 1;
                  tap(ki, __shfl(nidx23, ki + 32, 64), ac3); }
    }

    float s0 = (ac0.x + ac0.y) + (ac0.z + ac0.w);
    float s1 = (ac1.x + ac1.y) + (ac1.z + ac1.w);
    float s2v = (ac2.x + ac2.y) + (ac2.z + ac2.w);
    float s3 = (ac3.x + ac3.y) + (ac3.z + ac3.w);
    s0 += __shfl_xor(s0, 32, 64);
    s1 += __shfl_xor(s1, 32, 64);
    s2v += __shfl_xor(s2v, 32, 64);
    s3 += __shfl_xor(s3, 32, 64);
    const float bv  = bias[sub];
    const float o01 = (half ? s1 : s0) + bv;   // point i0+half
    const float o23 = (half ? s3 : s2v) + bv;  // point i0+2+half
    Yp[(size_t)(i0 + half) * 32 + sub]     = (_Float16)o01;
    Yp[(size_t)(i0 + 2 + half) * 32 + sub] = (_Float16)o23;

    // fused BN stats into NREP slabs
    __shared__ float sd[256];
    const int tid = threadIdx.x;
    float* __restrict__ slab = slab0 + (size_t)(blockIdx.x & (NREP - 1)) * 64;
    sd[tid] = o01 + o23;
    __syncthreads();
    if (tid < 32) {
        float t = 0.f;
#pragma unroll
        for (int k = 0; k < 8; ++k) t += sd[tid + 32 * k];
        atomicAdd(slab + tid, t);
    }
    __syncthreads();
    sd[tid] = o01 * o01 + o23 * o23;
    __syncthreads();
    if (tid < 32) {
        float t = 0.f;
#pragma unroll
        for (int k = 0; k < 8; ++k) t += sd[tid + 32 * k];
        atomicAdd(slab + 32 + tid, t);
    }
}

// ------ strided down conv: LDS grid rows, 4-chain, scalar feature base ------
// R11 structure (readfirstlane -> s_load feature path, 256 thr, 22 waves/CU);
// only change: float4 accumulators shorten the per-tap dep chain 16 -> 4.
__global__ __launch_bounds__(256) void k_down(const unsigned* __restrict__ X16,
                                              const int* __restrict__ grid,
                                              const uint4* __restrict__ Wh3,
                                              const float* __restrict__ bias,
                                              _Float16* __restrict__ Yh,
                                              unsigned char* __restrict__ mask,
                                              float* __restrict__ slab0,
                                              int* __restrict__ nacts) {
    const int b    = blockIdx.x;
    const int swz  = (b & 7) * (NB_DOWN / 8) + (b >> 3);
    const int tid  = threadIdx.x;
    const int wv   = tid >> 6;
    const int lane = tid & 63;
    const int sub  = lane & 31;
    const int half = lane >> 5;

    const int vox0 = swz * 64;
    const int ox0  = vox0 & 127;      // 0 or 64
    int t = vox0 >> 7;
    const int oy = t & 127; t >>= 7;
    const int oz = t & 15;
    const int bb = t >> 4;

    __shared__ int   gl[9][132];
    __shared__ float sd[256];
    __shared__ int   scnt[4];

    const int gx0 = 2 * ox0 - 1;
    for (int e = tid; e < 9 * 132; e += 256) {
        const int r  = e / 132, xo = e % 132;
        const int z  = 2 * oz - 1 + r / 3;
        const int y  = 2 * oy - 1 + r % 3;
        const int x  = gx0 + xo;
        int v = -1;
        if ((unsigned)z < (unsigned)D_ && (unsigned)y < (unsigned)H_ &&
            (unsigned)x < (unsigned)W_ && xo < 129)
            v = grid[((bb * D_ + z) * H_ + y) * W_ + x];
        gl[r][xo] = v;
    }
    __syncthreads();

    const int dz = sub / 9, dy = (sub / 3) % 3, dx = sub % 3;
    const int row = (sub < 27) ? dz * 3 + dy : 0;

    const float bv = bias[lane];
    float s = 0.f, s2 = 0.f;
    int cnt = 0;

    auto tap = [&](int ki, int ni, float4& ac) {
        const uint4* __restrict__ fS = (const uint4*)(X16 + (size_t)ni * 16);
        const uint4* __restrict__ wb = Wh3 + (size_t)ki * 256 + lane;
#pragma unroll
        for (int q = 0; q < 4; ++q) {
            const uint4 fu = fS[q];
            const uint4 wu = wb[q * 64];
            ac.x = dot2(fu.x, wu.x, ac.x);
            ac.y = dot2(fu.y, wu.y, ac.y);
            ac.z = dot2(fu.z, wu.z, ac.z);
            ac.w = dot2(fu.w, wu.w, ac.w);
        }
    };

    for (int it = 0; it < 4; ++it) {
        const int v0 = wv * 16 + it * 4;   // 4 voxels this iteration
        const int n01 = (sub < 27) ? gl[row][2 * (v0 + half) + dx] : -1;
        const int n23 = (sub < 27) ? gl[row][2 * (v0 + 2 + half) + dx] : -1;
        const unsigned long long a01 = __ballot(n01 >= 0);
        const unsigned long long a23 = __ballot(n23 >= 0);
        unsigned m0 = (unsigned)a01 & 0x7FFFFFFu;
        unsigned m1 = (unsigned)(a01 >> 32) & 0x7FFFFFFu;
        unsigned m2 = (unsigned)a23 & 0x7FFFFFFu;
        unsigned m3 = (unsigned)(a23 >> 32) & 0x7FFFFFFu;
        const int mk0 = m0 ? 1 : 0, mk1 = m1 ? 1 : 0;
        const int mk2 = m2 ? 1 : 0, mk3 = m3 ? 1 : 0;

        float4 ac0 = {0.f, 0.f, 0.f, 0.f}, ac1 = {0.f, 0.f, 0.f, 0.f};
        float4 ac2 = {0.f, 0.f, 0.f, 0.f}, ac3 = {0.f, 0.f, 0.f, 0.f};
        while (m0 | m1 | m2 | m3) {
            if (m0) { const int ki = __builtin_ctz(m0); m0 &= m0 - 1;
                      tap(ki, __builtin_amdgcn_readfirstlane(__shfl(n01, ki, 64)),      ac0); }
            if (m1) { const int ki = __builtin_ctz(m1); m1 &= m1 - 1;
                      tap(ki, __builtin_amdgcn_readfirstlane(__shfl(n01, ki + 32, 64)), ac1); }
            if (m2) { const int ki = __builtin_ctz(m2); m2 &= m2 - 1;
                      tap(ki, __builtin_amdgcn_readfirstlane(__shfl(n23, ki, 64)),      ac2); }
            if (m3) { const int ki = __builtin_ctz(m3); m3 &= m3 - 1;
                      tap(ki, __builtin_amdgcn_readfirstlane(__shfl(n23, ki + 32, 64)), ac3); }
        }

        const int vg = vox0 + v0;
        const float o0 = mk0 ? (ac0.x + ac0.y) + (ac0.z + ac0.w) + bv : 0.f;
        const float o1 = mk1 ? (ac1.x + ac1.y) + (ac1.z + ac1.w) + bv : 0.f;
        const float o2 = mk2 ? (ac2.x + ac2.y) + (ac2.z + ac2.w) + bv : 0.f;
        const float o3 = mk3 ? (ac3.x + ac3.y) + (ac3.z + ac3.w) + bv : 0.f;
        Yh[(size_t)vg * COUT + lane]       = (_Float16)o0;
        Yh[(size_t)(vg + 1) * COUT + lane] = (_Float16)o1;
        Yh[(size_t)(vg + 2) * COUT + lane] = (_Float16)o2;
        Yh[(size_t)(vg + 3) * COUT + lane] = (_Float16)o3;
        if (lane == 0) {
            mask[vg]     = (unsigned char)mk0;
            mask[vg + 1] = (unsigned char)mk1;
            mask[vg + 2] = (unsigned char)mk2;
            mask[vg + 3] = (unsigned char)mk3;
            cnt += mk0 + mk1 + mk2 + mk3;
        }
        s  += o0 + o1 + o2 + o3;
        s2 += o0 * o0 + o1 * o1 + o2 * o2 + o3 * o3;
    }

    float* __restrict__ slab = slab0 + (size_t)(b & (NREP - 1)) * 128;
    sd[tid] = s;
    if (lane == 0) scnt[wv] = cnt;
    __syncthreads();
    if (tid < 64) atomicAdd(slab + tid, sd[tid] + sd[tid + 64] + sd[tid + 128] + sd[tid + 192]);
    __syncthreads();
    sd[tid] = s2;
    __syncthreads();
    if (tid < 64) atomicAdd(slab + 64 + tid, sd[tid] + sd[tid + 64] + sd[tid + 128] + sd[tid + 192]);
    if (tid == 0) atomicAdd(nacts + (b & (NREP - 1)), scnt[0] + scnt[1] + scnt[2] + scnt[3]);
}

// ---------------- finalize scale/shift from NREP slabs (stages 1,2) ---------
template <int C>
__global__ void k_finslab(const float* __restrict__ slab0,
                          const float* __restrict__ g,
                          const float* __restrict__ be,
                          float n, float* __restrict__ ss) {
    const int c = threadIdx.x;
    if (c >= C) return;
    float sm = 0.f, s2 = 0.f;
    for (int r = 0; r < NREP; ++r) {
        sm += slab0[r * 2 * C + c];
        s2 += slab0[r * 2 * C + C + c];
    }
    const float m  = sm / n;
    const float v  = s2 / n - m * m;
    const float sc = g[c] * rsqrtf(v + EPSf);
    ss[c]     = sc;
    ss[C + c] = be[c] - m * sc;
}

// ---------------- finalize scale/shift (stage 3, folds NREP replicas) -------
__global__ void k_finstats3(const float* __restrict__ slab0,
                            const int* __restrict__ nacts,
                            const float* __restrict__ g,
                            const float* __restrict__ be,
                            float* __restrict__ ss) {
    const int c = threadIdx.x;   // 64 threads
    if (c >= 64) return;
    float sm = 0.f, s2 = 0.f;
    int na = 0;
    for (int r = 0; r < NREP; ++r) {
        sm += slab0[r * 128 + c];
        s2 += slab0[r * 128 + 64 + c];
        na += nacts[r];
    }
    const float n  = (float)(na > 0 ? na : 1);
    const float m  = sm / n;
    const float v  = s2 / n - m * m;
    const float sc = g[c] * rsqrtf(v + EPSf);
    ss[c]      = sc;
    ss[64 + c] = be[c] - m * sc;
}

// --------- normalize (BN+ReLU): fp16 pre-norm in -> packed fp16 out ---------
template <int C>
__global__ __launch_bounds__(256) void k_norm16(const unsigned* __restrict__ Yp2,
                                                const float* __restrict__ ss,
                                                unsigned* __restrict__ Xo16, long n4) {
    const long t = (long)blockIdx.x * 256 + threadIdx.x;
    if (t >= n4) return;
    const uint2 y = ((const uint2*)Yp2)[t];
    const h2 lo = as_h2(y.x), hi = as_h2(y.y);
    const int ch = (int)((t * 4) % C);
    float ox = fmaxf(fmaf((float)lo.x, ss[ch],     ss[C + ch]),     0.f);
    float oy = fmaxf(fmaf((float)lo.y, ss[ch + 1], ss[C + ch + 1]), 0.f);
    float oz = fmaxf(fmaf((float)hi.x, ss[ch + 2], ss[C + ch + 2]), 0.f);
    float ow = fmaxf(fmaf((float)hi.y, ss[ch + 3], ss[C + ch + 3]), 0.f);
    uint2 o; o.x = hpk(ox, oy); o.y = hpk(oz, ow);
    ((uint2*)Xo16)[t] = o;
}

// ---------------- stage-3 normalize: fp16 in, fp32 out ----------------
__global__ __launch_bounds__(256) void k_norm3(const _Float16* __restrict__ Yh,
                                               const unsigned char* __restrict__ mask,
                                               const float* __restrict__ ss,
                                               float* __restrict__ out) {
    const long n4 = (long)M_ * COUT / 4;
    const long t = (long)blockIdx.x * 256 + threadIdx.x;
    if (t >= n4) return;
    const long vox = t >> 4;
    const int ch = (int)((t * 4) & 63);
    float4 o;
    if (mask[vox]) {
        const uint2 yu = *(const uint2*)(Yh + t * 4);
        const h2 ylo = as_h2(yu.x), yhi = as_h2(yu.y);
        o.x = fmaxf(fmaf((float)ylo.x, ss[ch],     ss[64 + ch]),     0.f);
        o.y = fmaxf(fmaf((float)ylo.y, ss[ch + 1], ss[64 + ch + 1]), 0.f);
        o.z = fmaxf(fmaf((float)yhi.x, ss[ch + 2], ss[64 + ch + 2]), 0.f);
        o.w = fmaxf(fmaf((float)yhi.y, ss[ch + 3], ss[64 + ch + 3]), 0.f);
    } else {
        o.x = o.y = o.z = o.w = 0.f;
    }
    ((float4*)out)[t] = o;
}

extern "C" void kernel_launch(void* const* d_in, const int* in_sizes, int n_in,
                              void* d_out, int out_size, void* d_ws, size_t ws_size,
                              hipStream_t stream) {
    const float* feats = (const float*)d_in[0];
    const int*   coords = (const int*)d_in[1];
    const float* W1 = (const float*)d_in[2];
    const float* b1 = (const float*)d_in[3];
    const float* g1 = (const float*)d_in[4];
    const float* be1 = (const float*)d_in[5];
    const float* W2 = (const float*)d_in[6];
    const float* b2 = (const float*)d_in[7];
    const float* g2 = (const float*)d_in[8];
    const float* be2 = (const float*)d_in[9];
    const float* W3 = (const float*)d_in[10];
    const float* b3 = (const float*)d_in[11];
    const float* g3 = (const float*)d_in[12];
    const float* be3 = (const float*)d_in[13];
    float* out = (float*)d_out;

    char* ws = (char*)d_ws;
    const size_t gridBytes = (size_t)B_ * D_ * H_ * W_ * 4;   // 16,777,216
    const size_t f16Bytes  = (size_t)N_ * CIN * 2;            //  4,800,000
    const size_t bufPBytes = (size_t)N_ * CMID * 2;           //  9,600,000
    const size_t YhBytes   = (size_t)M_ * COUT * 2;           // 67,108,864
    int*       grid   = (int*)ws;
    unsigned*  feat16 = (unsigned*)(ws + gridBytes);
    _Float16*  bufP   = (_Float16*)(ws + gridBytes + f16Bytes);             // pre-norm
    unsigned*  bufH   = (unsigned*)(ws + gridBytes + f16Bytes + bufPBytes); // normalized
    _Float16*  Yh     = (_Float16*)(ws + gridBytes + f16Bytes + 2 * bufPBytes);
    unsigned char* mask = (unsigned char*)(ws + gridBytes + f16Bytes + 2 * bufPBytes + YhBytes);
    float* stats = (float*)(ws + gridBytes + f16Bytes + 2 * bufPBytes + YhBytes + (size_t)M_);

    float* ss1   = stats;                 // 64
    float* ss2   = stats + 64;            // 64
    float* ss3   = stats + 128;           // 128
    float* slab1 = stats + 1024;                        // NREP*64
    float* slab2 = stats + 1024 + NREP * 64;            // NREP*64
    float* slab3 = stats + 1024 + NREP * 128;           // NREP*128
    int*   nacts = (int*)(stats + 1024 + NREP * 256);   // NREP ints
    uint4* Wh1 = (uint4*)(stats + 32768);               // 1728 uint4
    uint4* Wh2 = Wh1 + 1728;                            // 3456 uint4
    uint4* Wh3 = Wh2 + 3456;                            // 6912 uint4

    hipMemsetAsync(grid, 0xFF, gridBytes, stream);
    hipMemsetAsync(stats + 1024, 0, (NREP * 256 + NREP) * 4, stream); // slabs+nacts

    k_scatter<<<(N_ + 255) / 256, 256, 0, stream>>>(coords, grid);
    k_twisth<<<(12096 + 255) / 256, 256, 0, stream>>>(W1, W2, W3, Wh1, Wh2, Wh3);
    k_feat16<<<(N_ * CIN / 4 + 255) / 256, 256, 0, stream>>>(feats, feat16);

    const int nb_subm = N_ / 16;   // 9375 blocks: 4 waves x 4 points, exact
    k_subm<CIN><<<nb_subm, 256, 0, stream>>>(feat16, coords, grid, Wh1, b1, bufP, slab1);
    k_finslab<CMID><<<1, 64, 0, stream>>>(slab1, g1, be1, (float)N_, ss1);
    k_norm16<CMID><<<(N_ * CMID / 4 + 255) / 256, 256, 0, stream>>>(
        (const unsigned*)bufP, ss1, bufH, (long)N_ * CMID / 4);

    k_subm<CMID><<<nb_subm, 256, 0, stream>>>(bufH, coords, grid, Wh2, b2, bufP, slab2);
    k_finslab<CMID><<<1, 64, 0, stream>>>(slab2, g2, be2, (float)N_, ss2);
    k_norm16<CMID><<<(N_ * CMID / 4 + 255) / 256, 256, 0, stream>>>(
        (const unsigned*)bufP, ss2, bufH, (long)N_ * CMID / 4);

    k_down<<<NB_DOWN, 256, 0, stream>>>(bufH, grid, Wh3, b3, Yh, mask, slab3, nacts);
    k_finstats3<<<1, 64, 0, stream>>>(slab3, nacts, g3, be3, ss3);
    k_norm3<<<(M_ * COUT / 4) / 256, 256, 0, stream>>>(Yh, mask, ss3, out);
}